// Round 1
// baseline (2467.248 us; speedup 1.0000x reference)
//
#include <hip/hip_runtime.h>
#include <hip/hip_bf16.h>

#define BATCH 32
#define CIN 128
#define HH 64
#define WW 64
#define MID 256
#define NCLS 65
#define HI 512

// ---------------------------------------------------------------------------
// Kernel 1: fused conv3x3+bias+relu -> 1x1 conv+bias -> softmax(65) ->
// pixel-shuffle -> conf threshold. Writes scores (B,512,512) to out.
// Block: 256 threads, one 4x4 pixel tile of one batch image.
// ---------------------------------------------------------------------------
__global__ __launch_bounds__(256) void head_kernel(
    const float* __restrict__ x, const float* __restrict__ w1,
    const float* __restrict__ b1, const float* __restrict__ w2,
    const float* __restrict__ b2, float* __restrict__ out)
{
    const int b  = blockIdx.z;
    const int y0 = blockIdx.y * 4;
    const int x0 = blockIdx.x * 4;
    const int tid = threadIdx.x;

    __shared__ float xp[CIN * 36];     // [c][dy*6+dx] patch incl halo 1
    __shared__ float hb[MID * 16];     // [m][p] hidden activations
    __shared__ float sem[16 * 66];     // [p][o] logits then exps (pad 66)
    __shared__ float rinv[16];         // 1/sum per pixel

    // ---- stage input patch (rows y0-1..y0+4, cols x0-1..x0+4, zero pad) ----
    const float* xb = x + (size_t)b * CIN * HH * WW;
    for (int i = tid; i < CIN * 36; i += 256) {
        int c = i / 36, r = i % 36;
        int yy = y0 - 1 + (r / 6), xx = x0 - 1 + (r % 6);
        float v = 0.f;
        if ((unsigned)yy < HH && (unsigned)xx < WW)
            v = xb[(c * HH + yy) * WW + xx];
        xp[i] = v;
    }
    __syncthreads();

    // ---- conv3x3: thread tid computes mid m = tid for all 16 pixels ----
    {
        const int m = tid;
        float acc[16];
        const float bb = b1[m];
#pragma unroll
        for (int p = 0; p < 16; ++p) acc[p] = bb;
        const float* wr = w1 + (size_t)m * CIN * 9;
        for (int c = 0; c < CIN; ++c) {
            float patch[36];
            const float4* xp4 = (const float4*)(xp + c * 36);
#pragma unroll
            for (int q = 0; q < 9; ++q) {
                float4 v = xp4[q];
                patch[q*4+0] = v.x; patch[q*4+1] = v.y;
                patch[q*4+2] = v.z; patch[q*4+3] = v.w;
            }
            float w[9];
#pragma unroll
            for (int k = 0; k < 9; ++k) w[k] = wr[c * 9 + k];
#pragma unroll
            for (int ky = 0; ky < 3; ++ky)
#pragma unroll
                for (int kx = 0; kx < 3; ++kx) {
                    const float wv = w[ky * 3 + kx];
#pragma unroll
                    for (int p = 0; p < 16; ++p) {
                        const int py = p >> 2, px = p & 3;
                        acc[p] += patch[(py + ky) * 6 + (px + kx)] * wv;
                    }
                }
        }
#pragma unroll
        for (int p = 0; p < 16; ++p) hb[m * 16 + p] = fmaxf(acc[p], 0.f);
    }
    __syncthreads();

    // ---- 1x1 conv: 65 outputs x 16 pixels = 1040 dot products of len 256 ----
    for (int t = tid; t < NCLS * 16; t += 256) {
        const int o = t >> 4, p = t & 15;
        float a = b2[o];
        const float* w2r = w2 + (size_t)o * MID;
#pragma unroll 8
        for (int mm = 0; mm < MID; ++mm)
            a += hb[mm * 16 + p] * w2r[mm];
        sem[p * 66 + o] = a;
    }
    __syncthreads();

    // ---- softmax per pixel (65 classes incl dust) ----
    if (tid < 16) {
        const int p = tid;
        float mx = -1e30f;
        for (int o = 0; o < NCLS; ++o) mx = fmaxf(mx, sem[p * 66 + o]);
        float s = 0.f;
        for (int o = 0; o < NCLS; ++o) {
            float e = __expf(sem[p * 66 + o] - mx);
            sem[p * 66 + o] = e;
            s += e;
        }
        rinv[p] = 1.f / s;
    }
    __syncthreads();

    // ---- pixel-shuffle write with conf threshold (classes 0..63 only) ----
    for (int t = tid; t < 16 * 64; t += 256) {
        const int p = t >> 6, o = t & 63;
        float v = sem[p * 66 + o] * rinv[p];
        if (!(v >= 0.015f)) v = 0.f;
        const int py = p >> 2, px = p & 3;
        const int row = (y0 + py) * 8 + (o >> 3);
        const int col = (x0 + px) * 8 + (o & 7);
        out[((size_t)b * HI + row) * HI + col] = v;
    }
}

// ---------------------------------------------------------------------------
// NMS init: M = (S == maxpool9x9(S)) && (S > 0).  Tile 64x64 + halo 4.
// Zero-padding is equivalent to -inf padding here since S >= 0 and the
// (S > 0) guard handles the all-zero-window case.
// ---------------------------------------------------------------------------
__global__ __launch_bounds__(256) void nms_init(
    const float* __restrict__ S, unsigned char* __restrict__ M)
{
    const int b = blockIdx.z;
    const int ty = blockIdx.y * 64, tx = blockIdx.x * 64;
    const int tid = threadIdx.x;
    __shared__ float s[72 * 72];
    __shared__ float rm[72 * 64];
    const float* Sb = S + (size_t)b * HI * HI;

    for (int i = tid; i < 72 * 72; i += 256) {
        int yy = ty - 4 + i / 72, xx = tx - 4 + i % 72;
        float v = 0.f;
        if ((unsigned)yy < HI && (unsigned)xx < HI) v = Sb[yy * HI + xx];
        s[i] = v;
    }
    __syncthreads();
    for (int i = tid; i < 72 * 64; i += 256) {
        int y = i / 64, x = i % 64;
        float mv = s[y * 72 + x];
#pragma unroll
        for (int k = 1; k < 9; ++k) mv = fmaxf(mv, s[y * 72 + x + k]);
        rm[i] = mv;
    }
    __syncthreads();
    for (int i = tid; i < 64 * 64; i += 256) {
        int y = i / 64, x = i % 64;
        float mv = rm[y * 64 + x];
#pragma unroll
        for (int k = 1; k < 9; ++k) mv = fmaxf(mv, rm[(y + k) * 64 + x]);
        float c = s[(y + 4) * 72 + (x + 4)];
        M[((size_t)b * HI + ty + y) * HI + tx + x] =
            (c == mv && c > 0.f) ? 1 : 0;
    }
}

// ---------------------------------------------------------------------------
// Dilate mask by radius 4 (9x9 OR): SUPP = maxpool9x9(M) > 0
// ---------------------------------------------------------------------------
__global__ __launch_bounds__(256) void nms_dilate(
    const unsigned char* __restrict__ M, unsigned char* __restrict__ SUPP)
{
    const int b = blockIdx.z;
    const int ty = blockIdx.y * 64, tx = blockIdx.x * 64;
    const int tid = threadIdx.x;
    __shared__ unsigned char sm[72 * 72];
    __shared__ unsigned char r8[72 * 64];
    const unsigned char* Mb = M + (size_t)b * HI * HI;

    for (int i = tid; i < 72 * 72; i += 256) {
        int yy = ty - 4 + i / 72, xx = tx - 4 + i % 72;
        unsigned char v = 0;
        if ((unsigned)yy < HI && (unsigned)xx < HI) v = Mb[yy * HI + xx];
        sm[i] = v;
    }
    __syncthreads();
    for (int i = tid; i < 72 * 64; i += 256) {
        int y = i / 64, x = i % 64;
        unsigned char v = 0;
#pragma unroll
        for (int k = 0; k < 9; ++k) v |= sm[y * 72 + x + k];
        r8[i] = v;
    }
    __syncthreads();
    for (int i = tid; i < 64 * 64; i += 256) {
        int y = i / 64, x = i % 64;
        unsigned char v = 0;
#pragma unroll
        for (int k = 0; k < 9; ++k) v |= r8[(y + k) * 64 + x];
        SUPP[((size_t)b * HI + ty + y) * HI + tx + x] = v ? 1 : 0;
    }
}

// ---------------------------------------------------------------------------
// One NMS sweep: ss = SUPP ? 0 : S; new_max = (ss == maxpool(ss)) && ss > 0;
// M |= new_max  (the & ~supp term is implied: supp => ss == 0 => fails ss>0).
// ---------------------------------------------------------------------------
__global__ __launch_bounds__(256) void nms_sweep(
    const float* __restrict__ S, const unsigned char* __restrict__ SUPP,
    unsigned char* __restrict__ M)
{
    const int b = blockIdx.z;
    const int ty = blockIdx.y * 64, tx = blockIdx.x * 64;
    const int tid = threadIdx.x;
    __shared__ float s[72 * 72];
    __shared__ float rm[72 * 64];
    const float* Sb = S + (size_t)b * HI * HI;
    const unsigned char* Pb = SUPP + (size_t)b * HI * HI;

    for (int i = tid; i < 72 * 72; i += 256) {
        int yy = ty - 4 + i / 72, xx = tx - 4 + i % 72;
        float v = 0.f;
        if ((unsigned)yy < HI && (unsigned)xx < HI) {
            int g = yy * HI + xx;
            v = Pb[g] ? 0.f : Sb[g];
        }
        s[i] = v;
    }
    __syncthreads();
    for (int i = tid; i < 72 * 64; i += 256) {
        int y = i / 64, x = i % 64;
        float mv = s[y * 72 + x];
#pragma unroll
        for (int k = 1; k < 9; ++k) mv = fmaxf(mv, s[y * 72 + x + k]);
        rm[i] = mv;
    }
    __syncthreads();
    for (int i = tid; i < 64 * 64; i += 256) {
        int y = i / 64, x = i % 64;
        float mv = rm[y * 64 + x];
#pragma unroll
        for (int k = 1; k < 9; ++k) mv = fmaxf(mv, rm[(y + k) * 64 + x]);
        float c = s[(y + 4) * 72 + (x + 4)];
        if (c == mv && c > 0.f)
            M[((size_t)b * HI + ty + y) * HI + tx + x] = 1;
    }
}

// ---------------------------------------------------------------------------
// Finalize: out = (M && border) ? S : 0, in place on d_out.
// ---------------------------------------------------------------------------
__global__ __launch_bounds__(256) void finalize_kernel(
    float* __restrict__ S, const unsigned char* __restrict__ M)
{
    const size_t i = (size_t)blockIdx.x * 256 + threadIdx.x;
    const size_t total = (size_t)BATCH * HI * HI;
    if (i >= total) return;
    const int yy = (int)((i >> 9) & 511);
    const int xx = (int)(i & 511);
    const bool bord = (yy >= 4) && (yy < HI - 4) && (xx >= 4) && (xx < HI - 4);
    const float v = S[i];
    S[i] = (M[i] && bord) ? v : 0.f;
}

extern "C" void kernel_launch(void* const* d_in, const int* in_sizes, int n_in,
                              void* d_out, int out_size, void* d_ws, size_t ws_size,
                              hipStream_t stream) {
    const float* x  = (const float*)d_in[0];
    const float* w1 = (const float*)d_in[1];
    const float* b1 = (const float*)d_in[2];
    const float* w2 = (const float*)d_in[3];
    const float* b2 = (const float*)d_in[4];
    float* out = (float*)d_out;

    unsigned char* M    = (unsigned char*)d_ws;
    unsigned char* SUPP = M + (size_t)BATCH * HI * HI;

    head_kernel<<<dim3(16, 16, BATCH), 256, 0, stream>>>(x, w1, b1, w2, b2, out);

    dim3 g(8, 8, BATCH);
    nms_init<<<g, 256, 0, stream>>>(out, M);
    for (int it = 0; it < 8; ++it) {
        nms_dilate<<<g, 256, 0, stream>>>(M, SUPP);
        nms_sweep<<<g, 256, 0, stream>>>(out, SUPP, M);
    }
    const size_t total = (size_t)BATCH * HI * HI;
    finalize_kernel<<<(int)((total + 255) / 256), 256, 0, stream>>>(out, M);
}

// Round 2
// 1902.998 us; speedup vs baseline: 1.2965x; 1.2965x over previous
//
#include <hip/hip_runtime.h>
#include <hip/hip_bf16.h>

#define BATCH 32
#define CIN 128
#define HH 64
#define WW 64
#define MID 256
#define NCLS 65
#define HI 512

// ---------------------------------------------------------------------------
// Transpose w1 [m][c][k] -> w1t [c*9+k][m] so conv weight loads coalesce.
// ---------------------------------------------------------------------------
__global__ __launch_bounds__(256) void transpose_w1(
    const float* __restrict__ w1, float* __restrict__ w1t)
{
    const int i = blockIdx.x * 256 + threadIdx.x;   // i = ck*256 + m
    if (i >= MID * CIN * 9) return;
    const int ck = i >> 8;          // 0..1151
    const int m  = i & 255;
    w1t[i] = w1[m * (CIN * 9) + ck];
}

// ---------------------------------------------------------------------------
// Fused conv3x3+bias+relu -> 1x1 conv+bias -> softmax(65) -> pixel-shuffle ->
// conf threshold. Block: 256 threads, one 4x4 pixel tile of one image.
// Weights read from transposed w1t: lane m reads w1t[ck*256+m] (coalesced).
// ---------------------------------------------------------------------------
__global__ __launch_bounds__(256) void head_kernel(
    const float* __restrict__ x, const float* __restrict__ w1t,
    const float* __restrict__ b1, const float* __restrict__ w2,
    const float* __restrict__ b2, float* __restrict__ out)
{
    const int b  = blockIdx.z;
    const int y0 = blockIdx.y * 4;
    const int x0 = blockIdx.x * 4;
    const int tid = threadIdx.x;

    __shared__ float xp[CIN * 36];      // [c][dy*6+dx] patch incl halo 1
    __shared__ float hb[MID * 17];      // [m][p] hidden, pad 17 (no conflicts)
    __shared__ float sem[16 * 66];      // [p][o] logits then exps
    __shared__ float rinv[16];

    // ---- stage input patch (rows y0-1..y0+4, cols x0-1..x0+4, zero pad) ----
    const float* xb = x + (size_t)b * CIN * HH * WW;
    for (int i = tid; i < CIN * 36; i += 256) {
        int c = i / 36, r = i % 36;
        int yy = y0 - 1 + (r / 6), xx = x0 - 1 + (r % 6);
        float v = 0.f;
        if ((unsigned)yy < HH && (unsigned)xx < WW)
            v = xb[(c * HH + yy) * WW + xx];
        xp[i] = v;
    }
    __syncthreads();

    // ---- conv3x3: thread tid owns mid m = tid for all 16 pixels ----
    {
        const int m = tid;
        float acc[16];
        const float bb = b1[m];
#pragma unroll
        for (int p = 0; p < 16; ++p) acc[p] = bb;
        for (int c = 0; c < CIN; ++c) {
            float w[9];
#pragma unroll
            for (int k = 0; k < 9; ++k)
                w[k] = w1t[(c * 9 + k) * MID + m];      // coalesced
            float patch[36];
            const float4* xp4 = (const float4*)(xp + c * 36);
#pragma unroll
            for (int q = 0; q < 9; ++q) {               // LDS broadcast reads
                float4 v = xp4[q];
                patch[q*4+0] = v.x; patch[q*4+1] = v.y;
                patch[q*4+2] = v.z; patch[q*4+3] = v.w;
            }
#pragma unroll
            for (int ky = 0; ky < 3; ++ky)
#pragma unroll
                for (int kx = 0; kx < 3; ++kx) {
                    const float wv = w[ky * 3 + kx];
#pragma unroll
                    for (int p = 0; p < 16; ++p) {
                        const int py = p >> 2, px = p & 3;
                        acc[p] += patch[(py + ky) * 6 + (px + kx)] * wv;
                    }
                }
        }
#pragma unroll
        for (int p = 0; p < 16; ++p) hb[m * 17 + p] = fmaxf(acc[p], 0.f);
    }
    __syncthreads();

    // ---- 1x1 conv: 65 outputs x 16 pixels, dot over 256 mids ----
    for (int t = tid; t < NCLS * 16; t += 256) {
        const int o = t >> 4, p = t & 15;
        float a = b2[o];
        const float* w2r = w2 + (size_t)o * MID;
#pragma unroll 8
        for (int mm = 0; mm < MID; ++mm)
            a += hb[mm * 17 + p] * w2r[mm];
        sem[p * 66 + o] = a;
    }
    __syncthreads();

    // ---- softmax per pixel (65 classes incl dust) ----
    if (tid < 16) {
        const int p = tid;
        float mx = -1e30f;
        for (int o = 0; o < NCLS; ++o) mx = fmaxf(mx, sem[p * 66 + o]);
        float s = 0.f;
        for (int o = 0; o < NCLS; ++o) {
            float e = __expf(sem[p * 66 + o] - mx);
            sem[p * 66 + o] = e;
            s += e;
        }
        rinv[p] = 1.f / s;
    }
    __syncthreads();

    // ---- pixel-shuffle write with conf threshold (classes 0..63) ----
    for (int t = tid; t < 16 * 64; t += 256) {
        const int p = t >> 6, o = t & 63;
        float v = sem[p * 66 + o] * rinv[p];
        if (!(v >= 0.015f)) v = 0.f;
        const int py = p >> 2, px = p & 3;
        const int row = (y0 + py) * 8 + (o >> 3);
        const int col = (x0 + px) * 8 + (o & 7);
        out[((size_t)b * HI + row) * HI + col] = v;
    }
}

// ---------------------------------------------------------------------------
// NMS init: M = (S == maxpool9x9(S)) && (S > 0).  Tile 64x64 + halo 4.
// ---------------------------------------------------------------------------
__global__ __launch_bounds__(256) void nms_init(
    const float* __restrict__ S, unsigned char* __restrict__ M)
{
    const int b = blockIdx.z;
    const int ty = blockIdx.y * 64, tx = blockIdx.x * 64;
    const int tid = threadIdx.x;
    __shared__ float s[72 * 72];
    __shared__ float rm[72 * 64];
    const float* Sb = S + (size_t)b * HI * HI;

    for (int i = tid; i < 72 * 72; i += 256) {
        int yy = ty - 4 + i / 72, xx = tx - 4 + i % 72;
        float v = 0.f;
        if ((unsigned)yy < HI && (unsigned)xx < HI) v = Sb[yy * HI + xx];
        s[i] = v;
    }
    __syncthreads();
    for (int i = tid; i < 72 * 64; i += 256) {
        int y = i / 64, x = i % 64;
        float mv = s[y * 72 + x];
#pragma unroll
        for (int k = 1; k < 9; ++k) mv = fmaxf(mv, s[y * 72 + x + k]);
        rm[i] = mv;
    }
    __syncthreads();
    for (int i = tid; i < 64 * 64; i += 256) {
        int y = i / 64, x = i % 64;
        float mv = rm[y * 64 + x];
#pragma unroll
        for (int k = 1; k < 9; ++k) mv = fmaxf(mv, rm[(y + k) * 64 + x]);
        float c = s[(y + 4) * 72 + (x + 4)];
        M[((size_t)b * HI + ty + y) * HI + tx + x] =
            (c == mv && c > 0.f) ? 1 : 0;
    }
}

// ---------------------------------------------------------------------------
// Dilate mask by radius 4 (9x9 OR): SUPP = maxpool9x9(M) > 0
// ---------------------------------------------------------------------------
__global__ __launch_bounds__(256) void nms_dilate(
    const unsigned char* __restrict__ M, unsigned char* __restrict__ SUPP)
{
    const int b = blockIdx.z;
    const int ty = blockIdx.y * 64, tx = blockIdx.x * 64;
    const int tid = threadIdx.x;
    __shared__ unsigned char sm[72 * 72];
    __shared__ unsigned char r8[72 * 64];
    const unsigned char* Mb = M + (size_t)b * HI * HI;

    for (int i = tid; i < 72 * 72; i += 256) {
        int yy = ty - 4 + i / 72, xx = tx - 4 + i % 72;
        unsigned char v = 0;
        if ((unsigned)yy < HI && (unsigned)xx < HI) v = Mb[yy * HI + xx];
        sm[i] = v;
    }
    __syncthreads();
    for (int i = tid; i < 72 * 64; i += 256) {
        int y = i / 64, x = i % 64;
        unsigned char v = 0;
#pragma unroll
        for (int k = 0; k < 9; ++k) v |= sm[y * 72 + x + k];
        r8[i] = v;
    }
    __syncthreads();
    for (int i = tid; i < 64 * 64; i += 256) {
        int y = i / 64, x = i % 64;
        unsigned char v = 0;
#pragma unroll
        for (int k = 0; k < 9; ++k) v |= r8[(y + k) * 64 + x];
        SUPP[((size_t)b * HI + ty + y) * HI + tx + x] = v ? 1 : 0;
    }
}

// ---------------------------------------------------------------------------
// One NMS sweep: ss = SUPP ? 0 : S; new_max = (ss == maxpool(ss)) && ss > 0;
// M |= new_max.
// ---------------------------------------------------------------------------
__global__ __launch_bounds__(256) void nms_sweep(
    const float* __restrict__ S, const unsigned char* __restrict__ SUPP,
    unsigned char* __restrict__ M)
{
    const int b = blockIdx.z;
    const int ty = blockIdx.y * 64, tx = blockIdx.x * 64;
    const int tid = threadIdx.x;
    __shared__ float s[72 * 72];
    __shared__ float rm[72 * 64];
    const float* Sb = S + (size_t)b * HI * HI;
    const unsigned char* Pb = SUPP + (size_t)b * HI * HI;

    for (int i = tid; i < 72 * 72; i += 256) {
        int yy = ty - 4 + i / 72, xx = tx - 4 + i % 72;
        float v = 0.f;
        if ((unsigned)yy < HI && (unsigned)xx < HI) {
            int g = yy * HI + xx;
            v = Pb[g] ? 0.f : Sb[g];
        }
        s[i] = v;
    }
    __syncthreads();
    for (int i = tid; i < 72 * 64; i += 256) {
        int y = i / 64, x = i % 64;
        float mv = s[y * 72 + x];
#pragma unroll
        for (int k = 1; k < 9; ++k) mv = fmaxf(mv, s[y * 72 + x + k]);
        rm[i] = mv;
    }
    __syncthreads();
    for (int i = tid; i < 64 * 64; i += 256) {
        int y = i / 64, x = i % 64;
        float mv = rm[y * 64 + x];
#pragma unroll
        for (int k = 1; k < 9; ++k) mv = fmaxf(mv, rm[(y + k) * 64 + x]);
        float c = s[(y + 4) * 72 + (x + 4)];
        if (c == mv && c > 0.f)
            M[((size_t)b * HI + ty + y) * HI + tx + x] = 1;
    }
}

// ---------------------------------------------------------------------------
// Finalize: out = (M && border) ? S : 0, in place on d_out.
// ---------------------------------------------------------------------------
__global__ __launch_bounds__(256) void finalize_kernel(
    float* __restrict__ S, const unsigned char* __restrict__ M)
{
    const size_t i = (size_t)blockIdx.x * 256 + threadIdx.x;
    const size_t total = (size_t)BATCH * HI * HI;
    if (i >= total) return;
    const int yy = (int)((i >> 9) & 511);
    const int xx = (int)(i & 511);
    const bool bord = (yy >= 4) && (yy < HI - 4) && (xx >= 4) && (xx < HI - 4);
    const float v = S[i];
    S[i] = (M[i] && bord) ? v : 0.f;
}

extern "C" void kernel_launch(void* const* d_in, const int* in_sizes, int n_in,
                              void* d_out, int out_size, void* d_ws, size_t ws_size,
                              hipStream_t stream) {
    const float* x  = (const float*)d_in[0];
    const float* w1 = (const float*)d_in[1];
    const float* b1 = (const float*)d_in[2];
    const float* w2 = (const float*)d_in[3];
    const float* b2 = (const float*)d_in[4];
    float* out = (float*)d_out;

    // ws layout: w1t (1.18 MB) lives in the SAME region as M — it is dead
    // by the time nms_init first writes M (stream ordering). Total ws use
    // stays 16.8 MB (the amount proven available in round 0).
    unsigned char* M    = (unsigned char*)d_ws;
    unsigned char* SUPP = M + (size_t)BATCH * HI * HI;
    float* w1t = (float*)d_ws;

    transpose_w1<<<(MID * CIN * 9 + 255) / 256, 256, 0, stream>>>(w1, w1t);
    head_kernel<<<dim3(16, 16, BATCH), 256, 0, stream>>>(x, w1t, b1, w2, b2, out);

    dim3 g(8, 8, BATCH);
    nms_init<<<g, 256, 0, stream>>>(out, M);
    for (int it = 0; it < 8; ++it) {
        nms_dilate<<<g, 256, 0, stream>>>(M, SUPP);
        nms_sweep<<<g, 256, 0, stream>>>(out, SUPP, M);
    }
    const size_t total = (size_t)BATCH * HI * HI;
    finalize_kernel<<<(int)((total + 255) / 256), 256, 0, stream>>>(out, M);
}